// Round 1
// baseline (6133.339 us; speedup 1.0000x reference)
//
#include <hip/hip_runtime.h>

#define B_ 16
#define T_ 2048
#define L_ 512
#define HD 200
#define AT 50

__device__ __forceinline__ float rcp_(float x){ return __builtin_amdgcn_rcpf(x); }
__device__ __forceinline__ float sigf(float x){ return rcp_(1.f + __expf(-x)); }
__device__ __forceinline__ float tanhf_(float x){
  x = fminf(15.f, fmaxf(-15.f, x));
  float e = __expf(-2.f*x);
  return (1.f - e) * rcp_(1.f + e);
}
__device__ __forceinline__ unsigned bf16u(float v){
  unsigned u = __float_as_uint(v);
  u += 0x7FFFu + ((u >> 16) & 1u);
  return u >> 16;
}
__device__ __forceinline__ unsigned long long pkvs(float v, unsigned s){
  return (unsigned long long)__float_as_uint(v) | ((unsigned long long)s << 32);
}
__device__ __forceinline__ unsigned long long ldU64(const unsigned long long* p){
  return __hip_atomic_load(p, __ATOMIC_RELAXED, __HIP_MEMORY_SCOPE_AGENT);
}

// ---------------- conv fold: E[3][256] ----------------
__global__ void k_prep(const float* __restrict__ conv1, const float* __restrict__ conv1a,
                       const float* __restrict__ conv2, const float* __restrict__ conv3,
                       float* __restrict__ E)
{
  __shared__ float K2s[3*256];
  int tid = threadIdx.x;            // 768 threads
  int k = tid >> 8, co = tid & 255;
  float a = 0.f;
  for (int ci = 0; ci < 256; ++ci)
    a = fmaf(conv1[ci], conv2[(k*256 + ci)*256 + co], a);
  K2s[k*256 + co] = a;
  __syncthreads();
  float b2 = 0.f;
  for (int ci = 0; ci < 256; ++ci)
    b2 = fmaf(K2s[k*256 + ci], conv3[ci*256 + co], b2);
  if (k == 1) b2 += conv1a[co];
  E[k*256 + co] = b2;
}

// ---------------- feat[b,t,256] ----------------
__global__ void k_feat(const float* __restrict__ sig, const float* __restrict__ E,
                       const float* __restrict__ c1ab, float* __restrict__ feat)
{
  int idx = blockIdx.x*256 + threadIdx.x;
  int row = idx >> 6;
  int c4  = (idx & 63) * 4;
  int t = row & (T_-1);
  float sm = (t > 0)     ? sig[row-1] : 0.f;
  float s0 = sig[row];
  float sp = (t < T_-1)  ? sig[row+1] : 0.f;
  float4 e0 = *(const float4*)&E[0*256 + c4];
  float4 e1 = *(const float4*)&E[1*256 + c4];
  float4 e2 = *(const float4*)&E[2*256 + c4];
  float4 bb = *(const float4*)&c1ab[c4];
  float4 r;
  r.x = fmaxf(0.f, fmaf(sm, e0.x, fmaf(s0, e1.x, fmaf(sp, e2.x, bb.x))));
  r.y = fmaxf(0.f, fmaf(sm, e0.y, fmaf(s0, e1.y, fmaf(sp, e2.y, bb.y))));
  r.z = fmaxf(0.f, fmaf(sm, e0.z, fmaf(s0, e1.z, fmaf(sp, e2.z, bb.z))));
  r.w = fmaxf(0.f, fmaf(sm, e0.w, fmaf(s0, e1.w, fmaf(sp, e2.w, bb.w))));
  *(float4*)&feat[(size_t)row*256 + c4] = r;
}

// ---------------- fp32 GEMM, 128x64 tile, 8x4 acc/thread ----------------
__global__ __launch_bounds__(256)
void k_gemm(const float* __restrict__ A, const float* __restrict__ B,
            const float* __restrict__ bias, float* __restrict__ C,
            int M, int N, int K, int ldb)
{
  __shared__ float As[16][132];
  __shared__ float Bs[16][68];
  int row0 = blockIdx.x*128, col0 = blockIdx.y*64;
  int tid = threadIdx.x;
  int tm = tid >> 4, tn = tid & 15;
  float acc[8][4] = {};
  for (int k0 = 0; k0 < K; k0 += 16){
    #pragma unroll
    for (int i = 0; i < 8; ++i){
      int e = tid + i*256;
      int m = e >> 4, kk = e & 15;
      float v = 0.f;
      if (k0 + kk < K) v = A[(size_t)(row0+m)*K + k0 + kk];
      As[kk][m] = v;
    }
    #pragma unroll
    for (int i = 0; i < 4; ++i){
      int e = tid + i*256;
      int n = e & 63, kb = e >> 6;
      float w = 0.f;
      if (k0 + kb < K && col0 + n < N) w = B[(size_t)(k0+kb)*ldb + col0 + n];
      Bs[kb][n] = w;
    }
    __syncthreads();
    #pragma unroll
    for (int kk = 0; kk < 16; ++kk){
      float a[8], bv[4];
      *(float4*)&a[0] = *(const float4*)&As[kk][tm*8];
      *(float4*)&a[4] = *(const float4*)&As[kk][tm*8+4];
      *(float4*)&bv[0] = *(const float4*)&Bs[kk][tn*4];
      #pragma unroll
      for (int i = 0; i < 8; ++i)
        #pragma unroll
        for (int j = 0; j < 4; ++j)
          acc[i][j] = fmaf(a[i], bv[j], acc[i][j]);
    }
    __syncthreads();
  }
  #pragma unroll
  for (int i = 0; i < 8; ++i){
    int r = row0 + tm*8 + i;
    #pragma unroll
    for (int j = 0; j < 4; ++j){
      int cc = col0 + tn*4 + j;
      if (cc < N) C[(size_t)r*N + cc] = acc[i][j] + (bias ? bias[cc] : 0.f);
    }
  }
}

// ---------------- weight permute for quad-gate encoder layout ----------------
__global__ void k_permW(const float* __restrict__ Wf, const float* __restrict__ bf,
                        const float* __restrict__ Wb, const float* __restrict__ bb,
                        float* __restrict__ WpF, float* __restrict__ WpB)
{
  int idx = blockIdx.x*256 + threadIdx.x;
  if (idx >= 2*357*400) return;
  int w = idx / (357*400), r = idx - w*(357*400);
  int j = r / 400, col = r - j*400;
  int src = (col & 3)*100 + (col >> 2);
  const float* W = w ? Wb : Wf; const float* bs = w ? bb : bf;
  float v = (j < 356) ? W[j*400 + src] : bs[src];
  (w ? WpB : WpF)[j*400 + col] = v;
}

// ---------------- standalone encoder (small-ws fallback path only) ----------------
__global__ __launch_bounds__(512, 1)
void k_encoder(const float* __restrict__ xprojF, const float* __restrict__ xprojB,
               const float* __restrict__ WpF, const float* __restrict__ WpB,
               const int* __restrict__ sig_len, float* __restrict__ memory,
               float* __restrict__ c0h0, int dirParam)
{
  int dir = dirParam, b = blockIdx.x;
  const float* xp = dir ? xprojB : xprojF;
  const float* Wp = dir ? WpB : WpF;
  int tid = threadIdx.x;
  bool act = tid < 400;
  int col = act ? tid : (tid - 400);
  int u = tid >> 2, gq = tid & 3;
  __shared__ __align__(16) float h2[2][104];
  float4 Uv[25];
  #pragma unroll
  for (int j4 = 0; j4 < 25; ++j4){
    Uv[j4].x = Wp[(256 + 4*j4 + 0)*400 + col];
    Uv[j4].y = Wp[(256 + 4*j4 + 1)*400 + col];
    Uv[j4].z = Wp[(256 + 4*j4 + 2)*400 + col];
    Uv[j4].w = Wp[(256 + 4*j4 + 3)*400 + col];
  }
  if (tid < 100) h2[0][tid] = 0.f;
  int len = sig_len[b];
  float c = 0.f, hfin = 0.f;
  int ta = dir ? (len-1) : 0;
  float xb0 = xp[((size_t)(b*T_ + ta))*400 + col];
  int tb_ = dir ? (len-2) : 1;
  float xb1 = xp[((size_t)(b*T_ + tb_))*400 + col];
  for (int step = 0; step < len; ++step){
    __syncthreads();
    int tn = dir ? (len-3-step) : (step+2);
    tn = tn < 0 ? 0 : (tn > T_-1 ? T_-1 : tn);
    float xn = xp[((size_t)(b*T_ + tn))*400 + col];
    const float* hb = h2[step & 1];
    float a0 = xb0, a1 = 0.f, a2 = 0.f, a3 = 0.f;
    #pragma unroll
    for (int j4 = 0; j4 < 25; ++j4){
      float4 h4 = *(const float4*)&hb[j4*4];
      a0 = fmaf(h4.x, Uv[j4].x, a0);
      a1 = fmaf(h4.y, Uv[j4].y, a1);
      a2 = fmaf(h4.z, Uv[j4].z, a2);
      a3 = fmaf(h4.w, Uv[j4].w, a3);
    }
    float z = (a0+a1)+(a2+a3);
    float v0 = z, v1 = __shfl_xor(z, 1);
    float v2 = __shfl_xor(v0, 2), v3 = __shfl_xor(v1, 2);
    float tA  = (gq&1) ? v1 : v0, tB  = (gq&1) ? v3 : v2;
    float tA2 = (gq&1) ? v0 : v1, tB2 = (gq&1) ? v2 : v3;
    float zi = (gq&2) ? tB  : tA;
    float zj = (gq&2) ? tB2 : tA2;
    float zf = (gq&2) ? tA  : tB;
    float zo = (gq&2) ? tA2 : tB2;
    c = c*sigf(zf + 1.f) + sigf(zi)*tanhf_(zj);
    float nh = tanhf_(c)*sigf(zo);
    hfin = nh;
    if (act && gq == 0){
      int t = dir ? (len-1-step) : step;
      h2[(step+1)&1][u] = nh;
      memory[((size_t)(b*T_ + t))*200 + dir*100 + u] = nh;
    }
    xb0 = xb1; xb1 = xn;
  }
  if (act && gq == 0){
    c0h0[b*400 + dir*100 + u]       = c;
    c0h0[b*400 + 200 + dir*100 + u] = hfin;
  }
  int total = (T_ - len)*100;
  for (int i = tid; i < total; i += 512){
    int t = len + i/100;
    int k = i - (i/100)*100;
    memory[((size_t)(b*T_ + t))*200 + dir*100 + k] = 0.f;
  }
}

// ---------------- decoder input gather ----------------
__global__ void k_gather(const float* __restrict__ emb, const int* __restrict__ labels,
                         float* __restrict__ dA)
{
  int idx = blockIdx.x*256 + threadIdx.x;
  int i = idx >> 6, e = idx & 63;
  dA[(size_t)i*64 + e] = emb[labels[i]*64 + e];
}

// ---------------- init: zero out + seq slots + flags ----------------
__global__ void k_dec_init(unsigned long long* __restrict__ nhb,
                           unsigned long long* __restrict__ parts,
                           unsigned* __restrict__ flags, unsigned fval,
                           float* __restrict__ out)
{
  int idx = blockIdx.x*256 + threadIdx.x;   // grid 192 -> 49152
  if (idx < B_*L_*6) out[idx] = 0.f;
  if (idx < B_*HD) nhb[idx] = 0ull;
  if (idx < B_*16*112) parts[idx] = 0ull;
  if (idx < 32) flags[idx] = fval;
}

// ================= fused encoder + keys + decoder, 512 threads =================
#define DEC_LDS 141440
#define TCH 128

__global__ __launch_bounds__(512, 1)
void k_fused(const float* __restrict__ xprojF, const float* __restrict__ xprojB,
             const float* __restrict__ WpF, const float* __restrict__ WpB,
             float* __restrict__ memG, float* c0h0,
             const float* __restrict__ W_mem, const float* __restrict__ W_attn,
             const float* __restrict__ decx, const float* __restrict__ W_dec,
             const float* __restrict__ W_out,
             const int* __restrict__ sig_len, const int* __restrict__ base_len,
             unsigned long long* nhb, unsigned long long* partials,
             unsigned* flags, int encInside,
             float* __restrict__ out)
{
  int blk = blockIdx.x;
  int b = (blk & 7) | (((blk >> 3) & 1) << 3);   // b's 16 blocks -> same XCD
  int g = blk >> 4;
  int tid = threadIdx.x;
  int u0 = g * 13;
  int nu = (HD - u0 < 13) ? (HD - u0) : 13;
  int t0 = g * TCH;

  extern __shared__ char smem[];
  uint2* keyP  = (uint2*)(smem);                 // [p<50][t<128+pad] stride 129 : 51600
  float* memAL = (float*)(smem + 51616);         // [128][50]
  float* Uld   = (float*)(smem + 77216);         // [250][52]; doubles as stg (51.2KB)
  float* Wa1s  = (float*)(smem + 129216);        // [13][50]
  float* WoutL = (float*)(smem + 131824);        // [50][6]
  float* nhF   = (float*)(smem + 133024);        // [208]
  float* spL   = (float*)(smem + 133856);        // [512]; doubles as encoder h2[2][104]
  float* wL    = (float*)(smem + 135904);        // [128]
  float* cpL   = (float*)(smem + 136416);        // [8][52] (7 used)
  float* apL   = (float*)(smem + 138080);        // [52]
  float* zp8T  = (float*)(smem + 138288);        // [8][56] (transposed zh partials)
  float* zpAT  = (float*)(smem + 140080);        // [4][56] (transposed za partials)
  float* attnL = (float*)(smem + 140976);        // [52]
  float* SL    = (float*)(smem + 141184);        // [2]
  float* opart = (float*)(smem + 141192);        // [60] out(l-1) partials (g==1)

  // ================= phase E: encoder (blocks g<2), 512-thread 1-col =================
  if (encInside && g < 2){
    int dir = g;
    const float* xp = dir ? xprojB : xprojF;
    const float* Wp = dir ? WpB : WpF;
    float* h2 = spL;                    // [2][104]
    bool act = tid < 400;
    int col = act ? tid : (tid - 400);
    int u = tid >> 2, gq = tid & 3;
    float4 Uv[25];
    #pragma unroll
    for (int j4 = 0; j4 < 25; ++j4){
      Uv[j4].x = Wp[(256 + 4*j4 + 0)*400 + col];
      Uv[j4].y = Wp[(256 + 4*j4 + 1)*400 + col];
      Uv[j4].z = Wp[(256 + 4*j4 + 2)*400 + col];
      Uv[j4].w = Wp[(256 + 4*j4 + 3)*400 + col];
    }
    if (tid < 104) { h2[tid] = 0.f; h2[104 + tid] = 0.f; }
    int len = sig_len[b];
    float c = 0.f, hfin = 0.f;
    // 4-deep x prefetch: HBM latency (~900cy) > slack at the old 2-deep pipeline
    int tP;
    tP = dir ? (len-1) : 0; tP = tP < 0 ? 0 : (tP > T_-1 ? T_-1 : tP);
    float xq0 = xp[((size_t)(b*T_ + tP))*400 + col];
    tP = dir ? (len-2) : 1; tP = tP < 0 ? 0 : (tP > T_-1 ? T_-1 : tP);
    float xq1 = xp[((size_t)(b*T_ + tP))*400 + col];
    tP = dir ? (len-3) : 2; tP = tP < 0 ? 0 : (tP > T_-1 ? T_-1 : tP);
    float xq2 = xp[((size_t)(b*T_ + tP))*400 + col];
    tP = dir ? (len-4) : 3; tP = tP < 0 ? 0 : (tP > T_-1 ? T_-1 : tP);
    float xq3 = xp[((size_t)(b*T_ + tP))*400 + col];
    for (int step = 0; step < len; ++step){
      __syncthreads();
      int tn = dir ? (len-5-step) : (step+4);
      tn = tn < 0 ? 0 : (tn > T_-1 ? T_-1 : tn);
      float xn = xp[((size_t)(b*T_ + tn))*400 + col];
      const float* hb = h2 + (step & 1)*104;
      float a0 = xq0, a1 = 0.f, a2 = 0.f, a3 = 0.f;
      #pragma unroll
      for (int j4 = 0; j4 < 25; ++j4){
        float4 h4 = *(const float4*)&hb[j4*4];
        a0 = fmaf(h4.x, Uv[j4].x, a0);
        a1 = fmaf(h4.y, Uv[j4].y, a1);
        a2 = fmaf(h4.z, Uv[j4].z, a2);
        a3 = fmaf(h4.w, Uv[j4].w, a3);
      }
      float z = (a0+a1)+(a2+a3);
      float v0 = z, v1 = __shfl_xor(z, 1);
      float v2 = __shfl_xor(v0, 2), v3 = __shfl_xor(v1, 2);
      float tA  = (gq&1) ? v1 : v0, tB  = (gq&1) ? v3 : v2;
      float tA2 = (gq&1) ? v0 : v1, tB2 = (gq&1) ? v2 : v3;
      float zi = (gq&2) ? tB  : tA;
      float zj = (gq&2) ? tB2 : tA2;
      float zf = (gq&2) ? tA  : tB;
      float zo = (gq&2) ? tA2 : tB2;
      c = c*sigf(zf + 1.f) + sigf(zi)*tanhf_(zj);
      float nh = tanhf_(c)*sigf(zo);
      hfin = nh;
      if (act && gq == 0){
        int t = dir ? (len-1-step) : step;
        h2[((step+1)&1)*104 + u] = nh;
        memG[((size_t)(b*T_ + t))*200 + dir*100 + u] = nh;
      }
      xq0 = xq1; xq1 = xq2; xq2 = xq3; xq3 = xn;
    }
    if (act && gq == 0){
      c0h0[b*400 + dir*100 + u]       = c;
      c0h0[b*400 + 200 + dir*100 + u] = hfin;
    }
    int total = (T_ - len)*100;
    for (int i = tid; i < total; i += 512){
      int t = len + i/100;
      int k = i - (i/100)*100;
      memG[((size_t)(b*T_ + t))*200 + dir*100 + k] = 0.f;
    }
    __syncthreads();
    if (tid == 0){
      __builtin_amdgcn_fence(__ATOMIC_RELEASE, "agent");
      __hip_atomic_store(&flags[b*2 + dir], 1u,
                         __ATOMIC_RELAXED, __HIP_MEMORY_SCOPE_AGENT);
    }
  }

  // ================= wait for encoder-b done =================
  if (encInside){
    if (tid == 0){
      while (__hip_atomic_load(&flags[b*2+0], __ATOMIC_RELAXED, __HIP_MEMORY_SCOPE_AGENT) == 0u)
        __builtin_amdgcn_s_sleep(8);
      while (__hip_atomic_load(&flags[b*2+1], __ATOMIC_RELAXED, __HIP_MEMORY_SCOPE_AGENT) == 0u)
        __builtin_amdgcn_s_sleep(8);
      __builtin_amdgcn_fence(__ATOMIC_ACQUIRE, "agent");
    }
    __syncthreads();
  }

  // ================= keys + memA for this block's t-chunk =================
  unsigned* stg = (unsigned*)Uld;       // [t<128][p2<100] bf16x2
  for (int i = tid; i < TCH*100; i += 512){
    int t = i / 100, p2 = i - (i/100)*100;
    float2 mv = *(const float2*)&memG[((size_t)(b*T_ + t0 + t))*200 + 2*p2];
    stg[i] = bf16u(mv.x) | (bf16u(mv.y) << 16);
  }
  __syncthreads();
  // keys: one (t, d-quad) unit per iteration
  for (int i = tid; i < TCH*50; i += 512){
    int t = i / 50, q = i - (i/50)*50;
    int d = q*4;
    const unsigned* mrow = stg + t*100;
    float ax = 0.f, ay = 0.f, az = 0.f, aw = 0.f;
    for (int p2 = 0; p2 < 100; ++p2){
      unsigned mm = mrow[p2];
      float m0 = __uint_as_float(mm << 16);
      float m1 = __uint_as_float(mm & 0xFFFF0000u);
      float4 w0 = *(const float4*)&W_mem[(size_t)(2*p2)*200 + d];
      float4 w1 = *(const float4*)&W_mem[(size_t)(2*p2+1)*200 + d];
      ax = fmaf(m0, w0.x, fmaf(m1, w1.x, ax));
      ay = fmaf(m0, w0.y, fmaf(m1, w1.y, ay));
      az = fmaf(m0, w0.z, fmaf(m1, w1.z, az));
      aw = fmaf(m0, w0.w, fmaf(m1, w1.w, aw));
    }
    keyP[q*129 + t] = make_uint2(bf16u(ax) | (bf16u(ay) << 16),
                                 bf16u(az) | (bf16u(aw) << 16));
  }
  // memA: one (t, d) unit per iteration
  for (int i = tid; i < TCH*50; i += 512){
    int t = i / 50, d = i - (i/50)*50;
    const unsigned* mrow = stg + t*100;
    float acc = 0.f;
    for (int p2 = 0; p2 < 100; ++p2){
      unsigned mm = mrow[p2];
      float m0 = __uint_as_float(mm << 16);
      float m1 = __uint_as_float(mm & 0xFFFF0000u);
      acc = fmaf(m0, W_attn[(size_t)(200 + 2*p2)*50 + d],
            fmaf(m1, W_attn[(size_t)(201 + 2*p2)*50 + d], acc));
    }
    memAL[t*50 + d] = acc;
  }
  __syncthreads();     // stg reads done before Uld overwrite

  // ================= one-time decoder fills =================
  for (int i = tid; i < 250*52; i += 512){
    int j = i / 52, o_ = i - (i/52)*52;
    int uu = o_ >> 2, gg = o_ & 3;
    Uld[i] = (uu < nu) ? W_dec[(size_t)(64 + j)*800 + gg*200 + u0 + uu] : 0.f;
  }
  for (int i = tid; i < 13*50; i += 512){
    int uw = i / 50, d = i - (i/50)*50;
    Wa1s[i] = (uw < nu) ? W_attn[(size_t)(u0 + uw)*50 + d] : 0.f;
  }
  for (int i = tid; i < 300; i += 512) WoutL[i] = W_out[i];
  if (tid < 52) attnL[tid] = 0.f;
  if (tid < 8)  nhF[200 + tid] = 0.f;
  float creg = (tid < nu) ? c0h0[b*400 + u0 + tid] : 0.f;
  int len = sig_len[b];
  int Lb  = base_len[b];
  unsigned long long* nhB = nhb + (size_t)b*HD;
  __syncthreads();

  // ---- pre-loop: nhF = h0; zh(0); dcx(0) ----
  if (tid < 50) *(float4*)&nhF[tid*4] = *(const float4*)&c0h0[b*400 + 200 + tid*4];
  __syncthreads();
  float dcx = 0.f;
  if (tid >= 96){
    int i = tid - 96;
    int o_ = i - (i/52)*52, j8 = i/52;
    const float* Ub = &Uld[(50 + j8*25)*52 + o_];
    const float* hp = &nhF[j8*25];
    float zh = 0.f;
    #pragma unroll
    for (int j = 0; j < 25; ++j) zh = fmaf(hp[j], Ub[(size_t)j*52], zh);
    zp8T[j8*56 + o_] = zh;
  }
  if (tid < 52)
    dcx = decx[((size_t)(b*L_))*800 + (tid&3)*200 + u0 + (tid>>2)];
  __syncthreads();

  for (int l = 0; l < Lb; ++l){
    unsigned seq = (unsigned)(l + 1);
    // ---- A: za gemv (attn rows, 4 chunks); g==1: out(l-1) partials (distributed)
    if (tid < 208){
      int o_ = tid - (tid/52)*52, jc4 = tid/52;
      float z = zp8T[(2*jc4)*56 + o_] + zp8T[(2*jc4+1)*56 + o_] + ((jc4 == 0) ? dcx : 0.f);
      const float* Ub = &Uld[(jc4*13)*52 + o_];
      const float* ap_ = &attnL[jc4*13];
      int cnt = (jc4 < 3) ? 13 : 11;
      for (int j = 0; j < cnt; ++j) z = fmaf(ap_[j], Ub[(size_t)j*52], z);
      zpAT[jc4*56 + o_] = z;
    } else if (g == 1 && l > 0 && tid >= 256 && tid < 316){
      int i = tid - 256, j = i - (i/6)*6, k = i/6;   // j<6, k<10: 5-d chunks
      float s = 0.f;
      #pragma unroll
      for (int d = 0; d < 5; ++d) s = fmaf(attnL[k*5 + d], WoutL[(k*5 + d)*6 + j], s);
      opart[i] = s;
    }
    __syncthreads();
    // ---- B: combine + activation; publish nh slice; wave1 reduces out(l-1)
    if (tid < nu){
      int c0 = tid*4;
      float zi = zpAT[c0  ] + zpAT[56+c0  ] + zpAT[112+c0  ] + zpAT[168+c0  ];
      float zj = zpAT[c0+1] + zpAT[56+c0+1] + zpAT[112+c0+1] + zpAT[168+c0+1];
      float zf = zpAT[c0+2] + zpAT[56+c0+2] + zpAT[112+c0+2] + zpAT[168+c0+2];
      float zo = zpAT[c0+3] + zpAT[56+c0+3] + zpAT[112+c0+3] + zpAT[168+c0+3];
      float c = creg;
      c = c*sigf(zf + 1.f) + sigf(zi)*tanhf_(zj);
      creg = c;
      float nh = tanhf_(c)*sigf(zo);
      __hip_atomic_store(&nhB[u0 + tid], pkvs(nh, seq),
                         __ATOMIC_RELAXED, __HIP_MEMORY_SCOPE_AGENT);
    } else if (g == 1 && l > 0 && tid >= 64 && tid < 70){
      int j = tid - 64;
      float o_ = 0.f;
      #pragma unroll
      for (int k = 0; k < 10; ++k) o_ += opart[k*6 + j];
      out[((size_t)(b*L_ + (l-1)))*6 + j] = o_;
    }
    // ---- C: wave0 batch-polls full nh vector (3-4 tagged values/lane, backoff)
    if (tid < 64){
      unsigned long long v0 = ldU64(&nhB[tid]);
      unsigned long long v1 = ldU64(&nhB[tid + 64]);
      unsigned long long v2 = ldU64(&nhB[tid + 128]);
      unsigned long long v3 = (tid < 8) ? ldU64(&nhB[tid + 192]) : 0ull;
      while ((unsigned)(v0 >> 32) != seq){ __builtin_amdgcn_s_sleep(1); v0 = ldU64(&nhB[tid]); }
      while ((unsigned)(v1 >> 32) != seq){ __builtin_amdgcn_s_sleep(1); v1 = ldU64(&nhB[tid + 64]); }
      while ((unsigned)(v2 >> 32) != seq){ __builtin_amdgcn_s_sleep(1); v2 = ldU64(&nhB[tid + 128]); }
      if (tid < 8)
        while ((unsigned)(v3 >> 32) != seq){ __builtin_amdgcn_s_sleep(1); v3 = ldU64(&nhB[tid + 192]); }
      nhF[tid]       = __uint_as_float((unsigned)v0);
      nhF[tid + 64]  = __uint_as_float((unsigned)v1);
      nhF[tid + 128] = __uint_as_float((unsigned)v2);
      if (tid < 8) nhF[tid + 192] = __uint_as_float((unsigned)v3);
    }
    __syncthreads();
    // ---- D: scores, 4-way split over key range
    {
      int t = tid & 127, dh = tid >> 7;            // dh wave-uniform
      int pstart = (dh < 2) ? dh*13 : 26 + (dh-2)*12;
      int pcnt   = (dh < 2) ? 13 : 12;
      const uint2* kp = &keyP[pstart*129 + t];
      const float4* nf = (const float4*)nhF + pstart;
      float s0 = 0.f, s1 = 0.f;
      for (int q = 0; q < pcnt; ++q){
        uint2 kk = kp[(size_t)q*129];
        float4 nv = nf[q];
        s0 = fmaf(nv.x, __uint_as_float(kk.x << 16), s0);
        s1 = fmaf(nv.y, __uint_as_float(kk.x & 0xFFFF0000u), s1);
        s0 = fmaf(nv.z, __uint_as_float(kk.y << 16), s0);
        s1 = fmaf(nv.w, __uint_as_float(kk.y & 0xFFFF0000u), s1);
      }
      spL[tid] = s0 + s1;
    }
    __syncthreads();
    // ---- E: w=exp ; ap gemv
    if (tid < 128){
      float s = (spL[tid] + spL[tid + 128]) + (spL[tid + 256] + spL[tid + 384]);
      float w = 0.f;
      if (t0 + tid < len){ s = fminf(60.f, fmaxf(-60.f, s)); w = __expf(s); }
      wL[tid] = w;
    } else if (tid < 178){
      int d = tid - 128;
      float a = 0.f;
      #pragma unroll
      for (int uw = 0; uw < 13; ++uw) a = fmaf(nhF[u0 + uw], Wa1s[uw*50 + d], a);
      apL[d] = a;
    }
    __syncthreads();
    // ---- F: ctx partials (7 chunks of 18/20 t) + S reduce (wave 7)
    if (tid >= 448){
      float v = wL[tid - 448] + wL[tid - 384];
      #pragma unroll
      for (int off = 32; off > 0; off >>= 1) v += __shfl_down(v, off);
      if (tid == 448) SL[0] = v;
    } else {
      int tc = tid >> 6, d = tid & 63;             // tc 0..6
      if (d < 50){
        int tlo = tc*18, thi = (tc == 6) ? 128 : tlo + 18;
        float a = 0.f;
        for (int t = tlo; t < thi; ++t) a = fmaf(wL[t], memAL[t*50 + d], a);
        cpL[tc*52 + d] = a;
      }
    }
    __syncthreads();
    // ---- G: publish partials; dcx prefetch; zh(l+1) on waves 1.5-8;
    //         wave0 batch-polls partials and computes attn(l) directly
    {
      unsigned long long* pb = partials + (size_t)(b*16 + g)*112;
      if (tid < 101){
        float p;
        if (tid < 50){
          p = 0.f;
          #pragma unroll
          for (int k = 0; k < 7; ++k) p += cpL[k*52 + tid];
        } else if (tid < 100) p = apL[tid - 50];
        else p = SL[0];
        __hip_atomic_store(&pb[tid], pkvs(p, seq),
                           __ATOMIC_RELAXED, __HIP_MEMORY_SCOPE_AGENT);
      }
    }
    if (tid < 52 && l+1 < Lb)
      dcx = decx[((size_t)(b*L_ + (l+1)))*800 + (tid&3)*200 + u0 + (tid>>2)];
    if (tid >= 96){
      int i = tid - 96;
      int o_ = i - (i/52)*52, j8 = i/52;
      const float* Ub = &Uld[(50 + j8*25)*52 + o_];
      const float* hp = &nhF[j8*25];
      float zh = 0.f;
      #pragma unroll
      for (int j = 0; j < 25; ++j) zh = fmaf(hp[j], Ub[(size_t)j*52], zh);
      zp8T[j8*56 + o_] = zh;
    }
    if (tid < 50){
      const unsigned long long* pbB = partials + (size_t)b*16*112;
      unsigned long long vc[16], va[16];
      #pragma unroll
      for (int g2 = 0; g2 < 16; ++g2){
        vc[g2] = ldU64(&pbB[g2*112 + tid]);
        va[g2] = ldU64(&pbB[g2*112 + 50 + tid]);
      }
      unsigned long long vs = (tid < 16) ? ldU64(&pbB[tid*112 + 100]) : 0ull;
      #pragma unroll
      for (int g2 = 0; g2 < 16; ++g2){
        while ((unsigned)(vc[g2] >> 32) != seq){
          __builtin_amdgcn_s_sleep(1); vc[g2] = ldU64(&pbB[g2*112 + tid]);
        }
        while ((unsigned)(va[g2] >> 32) != seq){
          __builtin_amdgcn_s_sleep(1); va[g2] = ldU64(&pbB[g2*112 + 50 + tid]);
        }
      }
      if (tid < 16)
        while ((unsigned)(vs >> 32) != seq){
          __builtin_amdgcn_s_sleep(1); vs = ldU64(&pbB[tid*112 + 100]);
        }
      float sp = (tid < 16) ? __uint_as_float((unsigned)vs) : 0.f;
      sp += __shfl_xor(sp, 1); sp += __shfl_xor(sp, 2);
      sp += __shfl_xor(sp, 4); sp += __shfl_xor(sp, 8);
      float ss = __shfl(sp, 0);
      float sc = 0.f, sa = 0.f;
      #pragma unroll
      for (int g2 = 0; g2 < 16; ++g2){
        sc += __uint_as_float((unsigned)vc[g2]);
        sa += __uint_as_float((unsigned)va[g2]);
      }
      attnL[tid] = fmaf(sc, rcp_(ss), sa);
    }
    __syncthreads();
  }
  // tail: out(Lb-1)
  if (g == 1 && tid < 6){
    float o_ = 0.f;
    for (int d = 0; d < AT; ++d) o_ = fmaf(attnL[d], WoutL[d*6 + tid], o_);
    out[((size_t)(b*L_ + (Lb-1)))*6 + tid] = o_;
  }
}

extern "C" void kernel_launch(void* const* d_in, const int* in_sizes, int n_in,
                              void* d_out, int out_size, void* d_ws, size_t ws_size,
                              hipStream_t stream)
{
  const float* signals   = (const float*)d_in[0];
  const float* embeddings= (const float*)d_in[1];
  const float* conv1_k   = (const float*)d_in[2];
  const float* conv1a_k  = (const float*)d_in[3];
  const float* conv1a_b  = (const float*)d_in[4];
  const float* conv2_k   = (const float*)d_in[5];
  const float* conv3_k   = (const float*)d_in[6];
  const float* W_fwd     = (const float*)d_in[7];
  const float* b_fwd     = (const float*)d_in[8];
  const float* W_bwd     = (const float*)d_in[9];
  const float* b_bwd     = (const float*)d_in[10];
  const float* W_dec     = (const float*)d_in[11];
  const float* b_dec     = (const float*)d_in[12];
  const float* W_mem     = (const float*)d_in[13];
  const float* W_attn    = (const float*)d_in[14];
  const float* W_out     = (const float*)d_in[15];
  const int*   labels    = (const int*)d_in[16];
  const int*   sig_len   = (const int*)d_in[17];
  const int*   base_len  = (const int*)d_in[18];
  float* out = (float*)d_out;
  char* ws = (char*)d_ws;

  const size_t o_c0h0     = 4096;
  const size_t o_nhbuf    = 32768;
  const size_t o_partials = 65536;
  const size_t o_flags    = 458752;
  const size_t o_WpF      = 589824;
  const size_t o_WpB      = 1161024;
  const size_t o_feat     = 4194304;
  const size_t o_mem      = o_feat + 33554432;
  const size_t o_X1       = o_mem + 26214400;
  const size_t o_X2       = o_X1 + 52428800;

  bool bigws = (ws_size >= o_X2 + 52428800);

  float* E      = (float*)(ws);
  float* c0h0   = (float*)(ws + o_c0h0);
  unsigned long long* nhbuf = (unsigned long long*)(ws + o_nhbuf);
  unsigned long long* parts = (unsigned long long*)(ws + o_partials);
  unsigned* flags = (unsigned*)(ws + o_flags);
  float* WpF    = (float*)(ws + o_WpF);
  float* WpB    = (float*)(ws + o_WpB);
  float* feat   = (float*)(ws + o_feat);
  float* memory = (float*)(ws + o_mem);
  float* xprojF = (float*)(ws + o_X1);
  float* xprojB = bigws ? (float*)(ws + o_X2) : xprojF;
  float* decxA  = (float*)(ws + o_feat);                 // overlay (feat dead)
  float* decx   = (float*)(ws + o_feat + 4194304);       // overlay (feat dead)

  k_prep<<<1, 768, 0, stream>>>(conv1_k, conv1a_k, conv2_k, conv3_k, E);
  k_feat<<<8192, 256, 0, stream>>>(signals, E, conv1a_b, feat);
  k_permW<<<1116, 256, 0, stream>>>(W_fwd, b_fwd, W_bwd, b_bwd, WpF, WpB);

  dim3 gx(256, 7);
  if (bigws){
    k_gemm<<<gx, 256, 0, stream>>>(feat, WpF, WpF + 356*400, xprojF, 32768, 400, 256, 400);
    k_gemm<<<gx, 256, 0, stream>>>(feat, WpB, WpB + 356*400, xprojB, 32768, 400, 256, 400);
  } else {
    k_gemm<<<gx, 256, 0, stream>>>(feat, WpF, WpF + 356*400, xprojF, 32768, 400, 256, 400);
    k_encoder<<<16, 512, 0, stream>>>(xprojF, xprojF, WpF, WpB, sig_len, memory, c0h0, 0);
    k_gemm<<<gx, 256, 0, stream>>>(feat, WpB, WpB + 356*400, xprojF, 32768, 400, 256, 400);
    k_encoder<<<16, 512, 0, stream>>>(xprojF, xprojF, WpF, WpB, sig_len, memory, c0h0, 1);
  }

  // feat dead now -> decxA/decx overlay safe
  k_gather<<<2048, 256, 0, stream>>>(embeddings, labels, decxA);
  k_gemm<<<dim3(64, 13), 256, 0, stream>>>(decxA, W_dec, b_dec, decx, 8192, 800, 64, 800);
  k_dec_init<<<192, 256, 0, stream>>>(nhbuf, parts, flags, bigws ? 0u : 1u, out);

  hipFuncSetAttribute(reinterpret_cast<const void*>(k_fused),
                      hipFuncAttributeMaxDynamicSharedMemorySize, DEC_LDS);
  k_fused<<<256, 512, DEC_LDS, stream>>>(xprojF, xprojB, WpF, WpB,
                                         memory, c0h0, W_mem, W_attn,
                                         decx, W_dec, W_out,
                                         sig_len, base_len,
                                         nhbuf, parts, flags, bigws ? 1 : 0,
                                         out);
}

// Round 2
// 4213.620 us; speedup vs baseline: 1.4556x; 1.4556x over previous
//
#include <hip/hip_runtime.h>

#define B_ 16
#define T_ 2048
#define L_ 512
#define HD 200
#define AT 50

__device__ __forceinline__ float rcp_(float x){ return __builtin_amdgcn_rcpf(x); }
__device__ __forceinline__ float sigf(float x){ return rcp_(1.f + __expf(-x)); }
__device__ __forceinline__ float tanhf_(float x){
  x = fminf(15.f, fmaxf(-15.f, x));
  float e = __expf(-2.f*x);
  return (1.f - e) * rcp_(1.f + e);
}
__device__ __forceinline__ unsigned bf16u(float v){
  unsigned u = __float_as_uint(v);
  u += 0x7FFFu + ((u >> 16) & 1u);
  return u >> 16;
}
__device__ __forceinline__ unsigned long long pkvs(float v, unsigned s){
  return (unsigned long long)__float_as_uint(v) | ((unsigned long long)s << 32);
}
__device__ __forceinline__ unsigned long long ldU64(const unsigned long long* p){
  return __hip_atomic_load(p, __ATOMIC_RELAXED, __HIP_MEMORY_SCOPE_AGENT);
}

// ---------------- conv fold: E[3][256] ----------------
__global__ void k_prep(const float* __restrict__ conv1, const float* __restrict__ conv1a,
                       const float* __restrict__ conv2, const float* __restrict__ conv3,
                       float* __restrict__ E)
{
  __shared__ float K2s[3*256];
  int tid = threadIdx.x;            // 768 threads
  int k = tid >> 8, co = tid & 255;
  float a = 0.f;
  for (int ci = 0; ci < 256; ++ci)
    a = fmaf(conv1[ci], conv2[(k*256 + ci)*256 + co], a);
  K2s[k*256 + co] = a;
  __syncthreads();
  float b2 = 0.f;
  for (int ci = 0; ci < 256; ++ci)
    b2 = fmaf(K2s[k*256 + ci], conv3[ci*256 + co], b2);
  if (k == 1) b2 += conv1a[co];
  E[k*256 + co] = b2;
}

// ---------------- feat[b,t,256] ----------------
__global__ void k_feat(const float* __restrict__ sig, const float* __restrict__ E,
                       const float* __restrict__ c1ab, float* __restrict__ feat)
{
  int idx = blockIdx.x*256 + threadIdx.x;
  int row = idx >> 6;
  int c4  = (idx & 63) * 4;
  int t = row & (T_-1);
  float sm = (t > 0)     ? sig[row-1] : 0.f;
  float s0 = sig[row];
  float sp = (t < T_-1)  ? sig[row+1] : 0.f;
  float4 e0 = *(const float4*)&E[0*256 + c4];
  float4 e1 = *(const float4*)&E[1*256 + c4];
  float4 e2 = *(const float4*)&E[2*256 + c4];
  float4 bb = *(const float4*)&c1ab[c4];
  float4 r;
  r.x = fmaxf(0.f, fmaf(sm, e0.x, fmaf(s0, e1.x, fmaf(sp, e2.x, bb.x))));
  r.y = fmaxf(0.f, fmaf(sm, e0.y, fmaf(s0, e1.y, fmaf(sp, e2.y, bb.y))));
  r.z = fmaxf(0.f, fmaf(sm, e0.z, fmaf(s0, e1.z, fmaf(sp, e2.z, bb.z))));
  r.w = fmaxf(0.f, fmaf(sm, e0.w, fmaf(s0, e1.w, fmaf(sp, e2.w, bb.w))));
  *(float4*)&feat[(size_t)row*256 + c4] = r;
}

// ---------------- fp32 GEMM, 128x64 tile, 8x4 acc/thread ----------------
__global__ __launch_bounds__(256)
void k_gemm(const float* __restrict__ A, const float* __restrict__ B,
            const float* __restrict__ bias, float* __restrict__ C,
            int M, int N, int K, int ldb)
{
  __shared__ float As[16][132];
  __shared__ float Bs[16][68];
  int row0 = blockIdx.x*128, col0 = blockIdx.y*64;
  int tid = threadIdx.x;
  int tm = tid >> 4, tn = tid & 15;
  float acc[8][4] = {};
  for (int k0 = 0; k0 < K; k0 += 16){
    #pragma unroll
    for (int i = 0; i < 8; ++i){
      int e = tid + i*256;
      int m = e >> 4, kk = e & 15;
      float v = 0.f;
      if (k0 + kk < K) v = A[(size_t)(row0+m)*K + k0 + kk];
      As[kk][m] = v;
    }
    #pragma unroll
    for (int i = 0; i < 4; ++i){
      int e = tid + i*256;
      int n = e & 63, kb = e >> 6;
      float w = 0.f;
      if (k0 + kb < K && col0 + n < N) w = B[(size_t)(k0+kb)*ldb + col0 + n];
      Bs[kb][n] = w;
    }
    __syncthreads();
    #pragma unroll
    for (int kk = 0; kk < 16; ++kk){
      float a[8], bv[4];
      *(float4*)&a[0] = *(const float4*)&As[kk][tm*8];
      *(float4*)&a[4] = *(const float4*)&As[kk][tm*8+4];
      *(float4*)&bv[0] = *(const float4*)&Bs[kk][tn*4];
      #pragma unroll
      for (int i = 0; i < 8; ++i)
        #pragma unroll
        for (int j = 0; j < 4; ++j)
          acc[i][j] = fmaf(a[i], bv[j], acc[i][j]);
    }
    __syncthreads();
  }
  #pragma unroll
  for (int i = 0; i < 8; ++i){
    int r = row0 + tm*8 + i;
    #pragma unroll
    for (int j = 0; j < 4; ++j){
      int cc = col0 + tn*4 + j;
      if (cc < N) C[(size_t)r*N + cc] = acc[i][j] + (bias ? bias[cc] : 0.f);
    }
  }
}

// ---------------- weight permute for quad-gate encoder layout ----------------
__global__ void k_permW(const float* __restrict__ Wf, const float* __restrict__ bf,
                        const float* __restrict__ Wb, const float* __restrict__ bb,
                        float* __restrict__ WpF, float* __restrict__ WpB)
{
  int idx = blockIdx.x*256 + threadIdx.x;
  if (idx >= 2*357*400) return;
  int w = idx / (357*400), r = idx - w*(357*400);
  int j = r / 400, col = r - j*400;
  int src = (col & 3)*100 + (col >> 2);
  const float* W = w ? Wb : Wf; const float* bs = w ? bb : bf;
  float v = (j < 356) ? W[j*400 + src] : bs[src];
  (w ? WpB : WpF)[j*400 + col] = v;
}

// ---------------- standalone encoder (small-ws fallback path only) ----------------
__global__ __launch_bounds__(512, 1)
void k_encoder(const float* __restrict__ xprojF, const float* __restrict__ xprojB,
               const float* __restrict__ WpF, const float* __restrict__ WpB,
               const int* __restrict__ sig_len, float* __restrict__ memory,
               float* __restrict__ c0h0, int dirParam)
{
  int dir = dirParam, b = blockIdx.x;
  const float* xp = dir ? xprojB : xprojF;
  const float* Wp = dir ? WpB : WpF;
  int tid = threadIdx.x;
  bool act = tid < 400;
  int col = act ? tid : (tid - 400);
  int u = tid >> 2, gq = tid & 3;
  __shared__ __align__(16) float h2[2][104];
  float4 Uv[25];
  #pragma unroll
  for (int j4 = 0; j4 < 25; ++j4){
    Uv[j4].x = Wp[(256 + 4*j4 + 0)*400 + col];
    Uv[j4].y = Wp[(256 + 4*j4 + 1)*400 + col];
    Uv[j4].z = Wp[(256 + 4*j4 + 2)*400 + col];
    Uv[j4].w = Wp[(256 + 4*j4 + 3)*400 + col];
  }
  if (tid < 100) h2[0][tid] = 0.f;
  int len = sig_len[b];
  float c = 0.f, hfin = 0.f;
  int ta = dir ? (len-1) : 0;
  float xb0 = xp[((size_t)(b*T_ + ta))*400 + col];
  int tb_ = dir ? (len-2) : 1;
  float xb1 = xp[((size_t)(b*T_ + tb_))*400 + col];
  for (int step = 0; step < len; ++step){
    __syncthreads();
    int tn = dir ? (len-3-step) : (step+2);
    tn = tn < 0 ? 0 : (tn > T_-1 ? T_-1 : tn);
    float xn = xp[((size_t)(b*T_ + tn))*400 + col];
    const float* hb = h2[step & 1];
    float a0 = xb0, a1 = 0.f, a2 = 0.f, a3 = 0.f;
    float b0 = 0.f, b1 = 0.f, b2 = 0.f, b3 = 0.f;
    #pragma unroll
    for (int j4 = 0; j4 < 12; ++j4){
      float4 h4 = *(const float4*)&hb[j4*4];
      a0 = fmaf(h4.x, Uv[j4].x, a0);
      a1 = fmaf(h4.y, Uv[j4].y, a1);
      a2 = fmaf(h4.z, Uv[j4].z, a2);
      a3 = fmaf(h4.w, Uv[j4].w, a3);
    }
    #pragma unroll
    for (int j4 = 12; j4 < 25; ++j4){
      float4 h4 = *(const float4*)&hb[j4*4];
      b0 = fmaf(h4.x, Uv[j4].x, b0);
      b1 = fmaf(h4.y, Uv[j4].y, b1);
      b2 = fmaf(h4.z, Uv[j4].z, b2);
      b3 = fmaf(h4.w, Uv[j4].w, b3);
    }
    float z = ((a0+b0)+(a1+b1)) + ((a2+b2)+(a3+b3));
    float v0 = z, v1 = __shfl_xor(z, 1);
    float v2 = __shfl_xor(v0, 2), v3 = __shfl_xor(v1, 2);
    float tA  = (gq&1) ? v1 : v0, tB  = (gq&1) ? v3 : v2;
    float tA2 = (gq&1) ? v0 : v1, tB2 = (gq&1) ? v2 : v3;
    float zi = (gq&2) ? tB  : tA;
    float zj = (gq&2) ? tB2 : tA2;
    float zf = (gq&2) ? tA  : tB;
    float zo = (gq&2) ? tA2 : tB2;
    c = c*sigf(zf + 1.f) + sigf(zi)*tanhf_(zj);
    float nh = tanhf_(c)*sigf(zo);
    hfin = nh;
    if (act && gq == 0){
      int t = dir ? (len-1-step) : step;
      h2[(step+1)&1][u] = nh;
      memory[((size_t)(b*T_ + t))*200 + dir*100 + u] = nh;
    }
    xb0 = xb1; xb1 = xn;
  }
  if (act && gq == 0){
    c0h0[b*400 + dir*100 + u]       = c;
    c0h0[b*400 + 200 + dir*100 + u] = hfin;
  }
  int total = (T_ - len)*100;
  for (int i = tid; i < total; i += 512){
    int t = len + i/100;
    int k = i - (i/100)*100;
    memory[((size_t)(b*T_ + t))*200 + dir*100 + k] = 0.f;
  }
}

// ---------------- decoder input gather ----------------
__global__ void k_gather(const float* __restrict__ emb, const int* __restrict__ labels,
                         float* __restrict__ dA)
{
  int idx = blockIdx.x*256 + threadIdx.x;
  int i = idx >> 6, e = idx & 63;
  dA[(size_t)i*64 + e] = emb[labels[i]*64 + e];
}

// ---------------- init: zero out + seq slots + flags ----------------
__global__ void k_dec_init(unsigned long long* __restrict__ nhb,
                           unsigned long long* __restrict__ parts,
                           unsigned* __restrict__ flags, unsigned fval,
                           float* __restrict__ out)
{
  int idx = blockIdx.x*256 + threadIdx.x;   // grid 192 -> 49152
  if (idx < B_*L_*6) out[idx] = 0.f;
  if (idx < B_*HD) nhb[idx] = 0ull;
  if (idx < B_*16*112) parts[idx] = 0ull;
  if (idx < 32) flags[idx] = fval;
}

// ================= fused encoder + keys + decoder, 512 threads =================
#define DEC_LDS 141696
#define TCH 128

__global__ __launch_bounds__(512, 1)
void k_fused(const float* __restrict__ xprojF, const float* __restrict__ xprojB,
             const float* __restrict__ WpF, const float* __restrict__ WpB,
             float* __restrict__ memG, float* c0h0,
             const float* __restrict__ W_mem, const float* __restrict__ W_attn,
             const float* __restrict__ decx, const float* __restrict__ W_dec,
             const float* __restrict__ W_out,
             const int* __restrict__ sig_len, const int* __restrict__ base_len,
             unsigned long long* nhb, unsigned long long* partials,
             unsigned* flags, int encInside,
             float* __restrict__ out)
{
  int blk = blockIdx.x;
  int b = (blk & 7) | (((blk >> 3) & 1) << 3);   // b's 16 blocks -> same XCD
  int g = blk >> 4;
  int tid = threadIdx.x;
  int u0 = g * 13;
  int nu = (HD - u0 < 13) ? (HD - u0) : 13;
  int t0 = g * TCH;

  extern __shared__ char smem[];
  uint2* keyP  = (uint2*)(smem);                 // [p<50][t<128+pad] stride 129 : 51600
  float* memAL = (float*)(smem + 51616);         // [128][50]
  float* Uld   = (float*)(smem + 77216);         // [250][52]; doubles as stg (51.2KB)
  float* Wa1s  = (float*)(smem + 129216);        // [13][50]
  float* WoutL = (float*)(smem + 131824);        // [50][6]
  float* nhF   = (float*)(smem + 133024);        // [208]
  float* spL   = (float*)(smem + 133856);        // [512]; doubles as encoder h2[2][104]
  float* wL    = (float*)(smem + 135904);        // [128]
  float* cpL   = (float*)(smem + 136416);        // [8][52] (7 used)
  float* apL   = (float*)(smem + 138080);        // [52]
  float* zp8T  = (float*)(smem + 138288);        // [8][56] (transposed zh partials)
  float* zpAT  = (float*)(smem + 140080);        // [4][56] (transposed za partials)
  float* ctxR  = (float*)(smem + 140976);        // [52]
  float* apR   = (float*)(smem + 141184);        // [52]
  float* SL    = (float*)(smem + 141392);        // [2]
  float* opart = (float*)(smem + 141400);        // [60] out(l-1) partials (g==1)

  // ================= phase E: encoder (blocks g<2), 512-thread 1-col =================
  if (encInside && g < 2){
    int dir = g;
    const float* xp = dir ? xprojB : xprojF;
    const float* Wp = dir ? WpB : WpF;
    float* h2 = spL;                    // [2][104]
    bool act = tid < 400;
    int col = act ? tid : (tid - 400);
    int u = tid >> 2, gq = tid & 3;
    float4 Uv[25];
    #pragma unroll
    for (int j4 = 0; j4 < 25; ++j4){
      Uv[j4].x = Wp[(256 + 4*j4 + 0)*400 + col];
      Uv[j4].y = Wp[(256 + 4*j4 + 1)*400 + col];
      Uv[j4].z = Wp[(256 + 4*j4 + 2)*400 + col];
      Uv[j4].w = Wp[(256 + 4*j4 + 3)*400 + col];
    }
    if (tid < 104) { h2[tid] = 0.f; h2[104 + tid] = 0.f; }
    int len = sig_len[b];
    float c = 0.f, hfin = 0.f;
    // 4-deep x prefetch: hides ~900cy HBM latency under ~3 LSTM steps
    int tP;
    tP = dir ? (len-1) : 0; tP = tP < 0 ? 0 : (tP > T_-1 ? T_-1 : tP);
    float xq0 = xp[((size_t)(b*T_ + tP))*400 + col];
    tP = dir ? (len-2) : 1; tP = tP < 0 ? 0 : (tP > T_-1 ? T_-1 : tP);
    float xq1 = xp[((size_t)(b*T_ + tP))*400 + col];
    tP = dir ? (len-3) : 2; tP = tP < 0 ? 0 : (tP > T_-1 ? T_-1 : tP);
    float xq2 = xp[((size_t)(b*T_ + tP))*400 + col];
    tP = dir ? (len-4) : 3; tP = tP < 0 ? 0 : (tP > T_-1 ? T_-1 : tP);
    float xq3 = xp[((size_t)(b*T_ + tP))*400 + col];
    for (int step = 0; step < len; ++step){
      __syncthreads();
      int tn = dir ? (len-5-step) : (step+4);
      tn = tn < 0 ? 0 : (tn > T_-1 ? T_-1 : tn);
      float xn = xp[((size_t)(b*T_ + tn))*400 + col];
      const float* hb = h2 + (step & 1)*104;
      float a0 = xq0, a1 = 0.f, a2 = 0.f, a3 = 0.f;
      float b0 = 0.f, b1 = 0.f, b2 = 0.f, b3 = 0.f;
      #pragma unroll
      for (int j4 = 0; j4 < 12; ++j4){
        float4 h4 = *(const float4*)&hb[j4*4];
        a0 = fmaf(h4.x, Uv[j4].x, a0);
        a1 = fmaf(h4.y, Uv[j4].y, a1);
        a2 = fmaf(h4.z, Uv[j4].z, a2);
        a3 = fmaf(h4.w, Uv[j4].w, a3);
      }
      #pragma unroll
      for (int j4 = 12; j4 < 25; ++j4){
        float4 h4 = *(const float4*)&hb[j4*4];
        b0 = fmaf(h4.x, Uv[j4].x, b0);
        b1 = fmaf(h4.y, Uv[j4].y, b1);
        b2 = fmaf(h4.z, Uv[j4].z, b2);
        b3 = fmaf(h4.w, Uv[j4].w, b3);
      }
      float z = ((a0+b0)+(a1+b1)) + ((a2+b2)+(a3+b3));
      float v0 = z, v1 = __shfl_xor(z, 1);
      float v2 = __shfl_xor(v0, 2), v3 = __shfl_xor(v1, 2);
      float tA  = (gq&1) ? v1 : v0, tB  = (gq&1) ? v3 : v2;
      float tA2 = (gq&1) ? v0 : v1, tB2 = (gq&1) ? v2 : v3;
      float zi = (gq&2) ? tB  : tA;
      float zj = (gq&2) ? tB2 : tA2;
      float zf = (gq&2) ? tA  : tB;
      float zo = (gq&2) ? tA2 : tB2;
      c = c*sigf(zf + 1.f) + sigf(zi)*tanhf_(zj);
      float nh = tanhf_(c)*sigf(zo);
      hfin = nh;
      if (act && gq == 0){
        int t = dir ? (len-1-step) : step;
        h2[((step+1)&1)*104 + u] = nh;
        memG[((size_t)(b*T_ + t))*200 + dir*100 + u] = nh;
      }
      xq0 = xq1; xq1 = xq2; xq2 = xq3; xq3 = xn;
    }
    if (act && gq == 0){
      c0h0[b*400 + dir*100 + u]       = c;
      c0h0[b*400 + 200 + dir*100 + u] = hfin;
    }
    int total = (T_ - len)*100;
    for (int i = tid; i < total; i += 512){
      int t = len + i/100;
      int k = i - (i/100)*100;
      memG[((size_t)(b*T_ + t))*200 + dir*100 + k] = 0.f;
    }
    __syncthreads();
    if (tid == 0){
      __builtin_amdgcn_fence(__ATOMIC_RELEASE, "agent");
      __hip_atomic_store(&flags[b*2 + dir], 1u,
                         __ATOMIC_RELAXED, __HIP_MEMORY_SCOPE_AGENT);
    }
  }

  // ================= wait for encoder-b done =================
  if (encInside){
    if (tid == 0){
      while (__hip_atomic_load(&flags[b*2+0], __ATOMIC_RELAXED, __HIP_MEMORY_SCOPE_AGENT) == 0u)
        __builtin_amdgcn_s_sleep(8);
      while (__hip_atomic_load(&flags[b*2+1], __ATOMIC_RELAXED, __HIP_MEMORY_SCOPE_AGENT) == 0u)
        __builtin_amdgcn_s_sleep(8);
      __builtin_amdgcn_fence(__ATOMIC_ACQUIRE, "agent");
    }
    __syncthreads();
  }

  // ================= keys + memA for this block's t-chunk =================
  unsigned* stg = (unsigned*)Uld;       // [t<128][p2<100] bf16x2
  for (int i = tid; i < TCH*100; i += 512){
    int t = i / 100, p2 = i - (i/100)*100;
    float2 mv = *(const float2*)&memG[((size_t)(b*T_ + t0 + t))*200 + 2*p2];
    stg[i] = bf16u(mv.x) | (bf16u(mv.y) << 16);
  }
  __syncthreads();
  // keys: one (t, d-quad) unit per iteration
  for (int i = tid; i < TCH*50; i += 512){
    int t = i / 50, q = i - (i/50)*50;
    int d = q*4;
    const unsigned* mrow = stg + t*100;
    float ax = 0.f, ay = 0.f, az = 0.f, aw = 0.f;
    for (int p2 = 0; p2 < 100; ++p2){
      unsigned mm = mrow[p2];
      float m0 = __uint_as_float(mm << 16);
      float m1 = __uint_as_float(mm & 0xFFFF0000u);
      float4 w0 = *(const float4*)&W_mem[(size_t)(2*p2)*200 + d];
      float4 w1 = *(const float4*)&W_mem[(size_t)(2*p2+1)*200 + d];
      ax = fmaf(m0, w0.x, fmaf(m1, w1.x, ax));
      ay = fmaf(m0, w0.y, fmaf(m1, w1.y, ay));
      az = fmaf(m0, w0.z, fmaf(m1, w1.z, az));
      aw = fmaf(m0, w0.w, fmaf(m1, w1.w, aw));
    }
    keyP[q*129 + t] = make_uint2(bf16u(ax) | (bf16u(ay) << 16),
                                 bf16u(az) | (bf16u(aw) << 16));
  }
  // memA: one (t, d) unit per iteration
  for (int i = tid; i < TCH*50; i += 512){
    int t = i / 50, d = i - (i/50)*50;
    const unsigned* mrow = stg + t*100;
    float acc = 0.f;
    for (int p2 = 0; p2 < 100; ++p2){
      unsigned mm = mrow[p2];
      float m0 = __uint_as_float(mm << 16);
      float m1 = __uint_as_float(mm & 0xFFFF0000u);
      acc = fmaf(m0, W_attn[(size_t)(200 + 2*p2)*50 + d],
            fmaf(m1, W_attn[(size_t)(201 + 2*p2)*50 + d], acc));
    }
    memAL[t*50 + d] = acc;
  }
  __syncthreads();     // stg reads done before Uld overwrite

  // ================= one-time decoder fills =================
  for (int i = tid; i < 250*52; i += 512){
    int j = i / 52, o_ = i - (i/52)*52;
    int uu = o_ >> 2, gg = o_ & 3;
    Uld[i] = (uu < nu) ? W_dec[(size_t)(64 + j)*800 + gg*200 + u0 + uu] : 0.f;
  }
  for (int i = tid; i < 13*50; i += 512){
    int uw = i / 50, d = i - (i/50)*50;
    Wa1s[i] = (uw < nu) ? W_attn[(size_t)(u0 + uw)*50 + d] : 0.f;
  }
  for (int i = tid; i < 300; i += 512) WoutL[i] = W_out[i];
  if (tid < 52){ ctxR[tid] = 0.f; apR[tid] = 0.f; }
  if (tid == 0){ SL[1] = 1.f; }          // rcp(1)=1; ctx=ap=0 -> attn(pre)=0
  if (tid < 8)  nhF[200 + tid] = 0.f;
  float creg = (tid < nu) ? c0h0[b*400 + u0 + tid] : 0.f;
  int len = sig_len[b];
  int Lb  = base_len[b];
  unsigned long long* nhB = nhb + (size_t)b*HD;
  __syncthreads();

  // ---- pre-loop: nhF = h0; zh(0); dcx(0) ----
  if (tid < 50) *(float4*)&nhF[tid*4] = *(const float4*)&c0h0[b*400 + 200 + tid*4];
  __syncthreads();
  float dcx = 0.f;
  if (tid < 416){
    int o_ = tid - (tid/52)*52, j8 = tid/52;
    const float* Ub = &Uld[(50 + j8*25)*52 + o_];
    const float* hp = &nhF[j8*25];
    float zA = 0.f, zB = 0.f;
    #pragma unroll
    for (int j = 0; j < 12; ++j) zA = fmaf(hp[j], Ub[(size_t)j*52], zA);
    #pragma unroll
    for (int j = 12; j < 25; ++j) zB = fmaf(hp[j], Ub[(size_t)j*52], zB);
    zp8T[j8*56 + o_] = zA + zB;
    if (tid < 52)
      dcx = decx[((size_t)(b*L_))*800 + (tid&3)*200 + u0 + (tid>>2)];
  }
  __syncthreads();

  for (int l = 0; l < Lb; ++l){
    unsigned seq = (unsigned)(l + 1);
    // ---- A: za gemv with inline attn (attn = ctx*rcp(S) + ap);
    //         g==1: out(l-1) partials (distributed, inline attn)
    float rs = rcp_(SL[1]);
    if (tid < 208){
      int o_ = tid - (tid/52)*52, jc4 = tid/52;
      float z  = zp8T[(2*jc4)*56 + o_] + ((jc4 == 0) ? dcx : 0.f);
      float z2 = zp8T[(2*jc4+1)*56 + o_];
      const float* Ub = &Uld[(jc4*13)*52 + o_];
      int j0 = jc4*13;
      int cnt = (jc4 < 3) ? 13 : 11;
      int j = 0;
      for (; j+1 < cnt; j += 2){
        float aj  = fmaf(ctxR[j0+j],   rs, apR[j0+j]);
        float aj2 = fmaf(ctxR[j0+j+1], rs, apR[j0+j+1]);
        z  = fmaf(aj,  Ub[(size_t)j*52], z);
        z2 = fmaf(aj2, Ub[(size_t)(j+1)*52], z2);
      }
      if (j < cnt){
        float aj = fmaf(ctxR[j0+j], rs, apR[j0+j]);
        z = fmaf(aj, Ub[(size_t)j*52], z);
      }
      zpAT[jc4*56 + o_] = z + z2;
    } else if (g == 1 && l > 0 && tid >= 256 && tid < 316){
      int i = tid - 256, j = i - (i/6)*6, k = i/6;   // j<6, k<10: 5-d chunks
      float s = 0.f;
      #pragma unroll
      for (int d = 0; d < 5; ++d){
        float ad = fmaf(ctxR[k*5 + d], rs, apR[k*5 + d]);
        s = fmaf(ad, WoutL[(k*5 + d)*6 + j], s);
      }
      opart[i] = s;
    }
    __syncthreads();
    // ---- B: combine + activation; publish nh slice; wave1 reduces out(l-1)
    if (tid < nu){
      int c0 = tid*4;
      float zi = zpAT[c0  ] + zpAT[56+c0  ] + zpAT[112+c0  ] + zpAT[168+c0  ];
      float zj = zpAT[c0+1] + zpAT[56+c0+1] + zpAT[112+c0+1] + zpAT[168+c0+1];
      float zf = zpAT[c0+2] + zpAT[56+c0+2] + zpAT[112+c0+2] + zpAT[168+c0+2];
      float zo = zpAT[c0+3] + zpAT[56+c0+3] + zpAT[112+c0+3] + zpAT[168+c0+3];
      float c = creg;
      c = c*sigf(zf + 1.f) + sigf(zi)*tanhf_(zj);
      creg = c;
      float nh = tanhf_(c)*sigf(zo);
      __hip_atomic_store(&nhB[u0 + tid], pkvs(nh, seq),
                         __ATOMIC_RELAXED, __HIP_MEMORY_SCOPE_AGENT);
    } else if (g == 1 && l > 0 && tid >= 64 && tid < 70){
      int j = tid - 64;
      float o_ = 0.f;
      #pragma unroll
      for (int k = 0; k < 10; ++k) o_ += opart[k*6 + j];
      out[((size_t)(b*L_ + (l-1)))*6 + j] = o_;
    }
    // ---- C: 200-thread tight spin on own nh value (fastest detection)
    if (tid < HD){
      unsigned long long v;
      do {
        v = ldU64(&nhB[tid]);
      } while ((unsigned)(v >> 32) != seq);
      nhF[tid] = __uint_as_float((unsigned)v);
    }
    __syncthreads();
    // ---- D: scores, 4-way split over key range (4 accumulators)
    {
      int t = tid & 127, dh = tid >> 7;            // dh wave-uniform
      int pstart = (dh < 2) ? dh*13 : 26 + (dh-2)*12;
      int pcnt   = (dh < 2) ? 13 : 12;
      const uint2* kp = &keyP[pstart*129 + t];
      const float4* nf = (const float4*)nhF + pstart;
      float s0 = 0.f, s1 = 0.f, s2 = 0.f, s3 = 0.f;
      int q = 0;
      for (; q+1 < pcnt; q += 2){
        uint2 k0 = kp[(size_t)q*129];
        uint2 k1 = kp[(size_t)(q+1)*129];
        float4 n0 = nf[q], n1 = nf[q+1];
        s0 = fmaf(n0.x, __uint_as_float(k0.x << 16), s0);
        s1 = fmaf(n0.y, __uint_as_float(k0.x & 0xFFFF0000u), s1);
        s0 = fmaf(n0.z, __uint_as_float(k0.y << 16), s0);
        s1 = fmaf(n0.w, __uint_as_float(k0.y & 0xFFFF0000u), s1);
        s2 = fmaf(n1.x, __uint_as_float(k1.x << 16), s2);
        s3 = fmaf(n1.y, __uint_as_float(k1.x & 0xFFFF0000u), s3);
        s2 = fmaf(n1.z, __uint_as_float(k1.y << 16), s2);
        s3 = fmaf(n1.w, __uint_as_float(k1.y & 0xFFFF0000u), s3);
      }
      if (q < pcnt){
        uint2 k0 = kp[(size_t)q*129];
        float4 n0 = nf[q];
        s0 = fmaf(n0.x, __uint_as_float(k0.x << 16), s0);
        s1 = fmaf(n0.y, __uint_as_float(k0.x & 0xFFFF0000u), s1);
        s0 = fmaf(n0.z, __uint_as_float(k0.y << 16), s0);
        s1 = fmaf(n0.w, __uint_as_float(k0.y & 0xFFFF0000u), s1);
      }
      spL[tid] = (s0 + s1) + (s2 + s3);
    }
    __syncthreads();
    // ---- E: w=exp ; ap gemv
    if (tid < 128){
      float s = (spL[tid] + spL[tid + 128]) + (spL[tid + 256] + spL[tid + 384]);
      float w = 0.f;
      if (t0 + tid < len){ s = fminf(60.f, fmaxf(-60.f, s)); w = __expf(s); }
      wL[tid] = w;
    } else if (tid < 178){
      int d = tid - 128;
      float a = 0.f;
      #pragma unroll
      for (int uw = 0; uw < 13; ++uw) a = fmaf(nhF[u0 + uw], Wa1s[uw*50 + d], a);
      apL[d] = a;
    }
    __syncthreads();
    // ---- F: ctx partials (7 chunks, 2 accumulators) + S reduce (wave 7)
    if (tid >= 448){
      float v = wL[tid - 448] + wL[tid - 384];
      #pragma unroll
      for (int off = 32; off > 0; off >>= 1) v += __shfl_down(v, off);
      if (tid == 448) SL[0] = v;
    } else {
      int tc = tid >> 6, d = tid & 63;             // tc 0..6
      if (d < 50){
        int tlo = tc*18, thi = (tc == 6) ? 128 : tlo + 18;
        float a = 0.f, a2 = 0.f;
        int t = tlo;
        for (; t+1 < thi; t += 2){
          a  = fmaf(wL[t],   memAL[t*50 + d], a);
          a2 = fmaf(wL[t+1], memAL[(t+1)*50 + d], a2);
        }
        if (t < thi) a = fmaf(wL[t], memAL[t*50 + d], a);
        cpL[tc*52 + d] = a + a2;
      }
    }
    __syncthreads();
    // ---- G: publish partials; dcx prefetch; zh(l+1); tight poll-reduce -> ctxR/apR/S
    {
      unsigned long long* pb = partials + (size_t)(b*16 + g)*112;
      if (tid < 101){
        float p;
        if (tid < 50){
          p = 0.f;
          #pragma unroll
          for (int k = 0; k < 7; ++k) p += cpL[k*52 + tid];
        } else if (tid < 100) p = apL[tid - 50];
        else p = SL[0];
        __hip_atomic_store(&pb[tid], pkvs(p, seq),
                           __ATOMIC_RELAXED, __HIP_MEMORY_SCOPE_AGENT);
      }
    }
    if (tid < 416){
      int o_ = tid - (tid/52)*52, j8 = tid/52;
      const float* Ub = &Uld[(50 + j8*25)*52 + o_];
      const float* hp = &nhF[j8*25];
      float zA = 0.f, zB = 0.f;
      #pragma unroll
      for (int j = 0; j < 12; ++j) zA = fmaf(hp[j], Ub[(size_t)j*52], zA);
      #pragma unroll
      for (int j = 12; j < 25; ++j) zB = fmaf(hp[j], Ub[(size_t)j*52], zB);
      zp8T[j8*56 + o_] = zA + zB;
      if (tid < 52 && l+1 < Lb)
        dcx = decx[((size_t)(b*L_ + (l+1)))*800 + (tid&3)*200 + u0 + (tid>>2)];
    }
    if (tid < 101){
      const unsigned long long* base = partials + (size_t)b*16*112 + tid;
      unsigned long long v[16];
      #pragma unroll
      for (int g2 = 0; g2 < 16; ++g2)
        v[g2] = ldU64(&base[g2*112]);
      #pragma unroll
      for (int g2 = 0; g2 < 16; ++g2)
        while ((unsigned)(v[g2] >> 32) != seq)
          v[g2] = ldU64(&base[g2*112]);
      float acc = 0.f;
      #pragma unroll
      for (int g2 = 0; g2 < 16; ++g2) acc += __uint_as_float((unsigned)v[g2]);
      if (tid < 50) ctxR[tid] = acc;
      else if (tid < 100) apR[tid - 50] = acc;
      else SL[1] = acc;
    }
    __syncthreads();
  }
  // tail: out(Lb-1), inline attn
  if (g == 1 && tid < 6){
    float rs = rcp_(SL[1]);
    float o_ = 0.f;
    for (int d = 0; d < AT; ++d)
      o_ = fmaf(fmaf(ctxR[d], rs, apR[d]), WoutL[d*6 + tid], o_);
    out[((size_t)(b*L_ + (Lb-1)))*6 + tid] = o_;
  }
}

extern "C" void kernel_launch(void* const* d_in, const int* in_sizes, int n_in,
                              void* d_out, int out_size, void* d_ws, size_t ws_size,
                              hipStream_t stream)
{
  const float* signals   = (const float*)d_in[0];
  const float* embeddings= (const float*)d_in[1];
  const float* conv1_k   = (const float*)d_in[2];
  const float* conv1a_k  = (const float*)d_in[3];
  const float* conv1a_b  = (const float*)d_in[4];
  const float* conv2_k   = (const float*)d_in[5];
  const float* conv3_k   = (const float*)d_in[6];
  const float* W_fwd     = (const float*)d_in[7];
  const float* b_fwd     = (const float*)d_in[8];
  const float* W_bwd     = (const float*)d_in[9];
  const float* b_bwd     = (const float*)d_in[10];
  const float* W_dec     = (const float*)d_in[11];
  const float* b_dec     = (const float*)d_in[12];
  const float* W_mem     = (const float*)d_in[13];
  const float* W_attn    = (const float*)d_in[14];
  const float* W_out     = (const float*)d_in[15];
  const int*   labels    = (const int*)d_in[16];
  const int*   sig_len   = (const int*)d_in[17];
  const int*   base_len  = (const int*)d_in[18];
  float* out = (float*)d_out;
  char* ws = (char*)d_ws;

  const size_t o_c0h0     = 4096;
  const size_t o_nhbuf    = 32768;
  const size_t o_partials = 65536;
  const size_t o_flags    = 458752;
  const size_t o_WpF      = 589824;
  const size_t o_WpB      = 1161024;
  const size_t o_feat     = 4194304;
  const size_t o_mem      = o_feat + 33554432;
  const size_t o_X1       = o_mem + 26214400;
  const size_t o_X2       = o_X1 + 52428800;

  bool bigws = (ws_size >= o_X2 + 52428800);

  float* E      = (float*)(ws);
  float* c0h0   = (float*)(ws + o_c0h0);
  unsigned long long* nhbuf = (unsigned long long*)(ws + o_nhbuf);
  unsigned long long* parts = (unsigned long long*)(ws + o_partials);
  unsigned* flags = (unsigned*)(ws + o_flags);
  float* WpF    = (float*)(ws + o_WpF);
  float* WpB    = (float*)(ws + o_WpB);
  float* feat   = (float*)(ws + o_feat);
  float* memory = (float*)(ws + o_mem);
  float* xprojF = (float*)(ws + o_X1);
  float* xprojB = bigws ? (float*)(ws + o_X2) : xprojF;
  float* decxA  = (float*)(ws + o_feat);                 // overlay (feat dead)
  float* decx   = (float*)(ws + o_feat + 4194304);       // overlay (feat dead)

  k_prep<<<1, 768, 0, stream>>>(conv1_k, conv1a_k, conv2_k, conv3_k, E);
  k_feat<<<8192, 256, 0, stream>>>(signals, E, conv1a_b, feat);
  k_permW<<<1116, 256, 0, stream>>>(W_fwd, b_fwd, W_bwd, b_bwd, WpF, WpB);

  dim3 gx(256, 7);
  if (bigws){
    k_gemm<<<gx, 256, 0, stream>>>(feat, WpF, WpF + 356*400, xprojF, 32768, 400, 256, 400);
    k_gemm<<<gx, 256, 0, stream>>>(feat, WpB, WpB + 356*400, xprojB, 32768, 400, 256, 400);
  } else {
    k_gemm<<<gx, 256, 0, stream>>>(feat, WpF, WpF + 356*400, xprojF, 32768, 400, 256, 400);
    k_encoder<<<16, 512, 0, stream>>>(xprojF, xprojF, WpF, WpB, sig_len, memory, c0h0, 0);
    k_gemm<<<gx, 256, 0, stream>>>(feat, WpB, WpB + 356*400, xprojF, 32768, 400, 256, 400);
    k_encoder<<<16, 512, 0, stream>>>(xprojF, xprojF, WpF, WpB, sig_len, memory, c0h0, 1);
  }

  // feat dead now -> decxA/decx overlay safe
  k_gather<<<2048, 256, 0, stream>>>(embeddings, labels, decxA);
  k_gemm<<<dim3(64, 13), 256, 0, stream>>>(decxA, W_dec, b_dec, decx, 8192, 800, 64, 800);
  k_dec_init<<<192, 256, 0, stream>>>(nhbuf, parts, flags, bigws ? 0u : 1u, out);

  hipFuncSetAttribute(reinterpret_cast<const void*>(k_fused),
                      hipFuncAttributeMaxDynamicSharedMemorySize, DEC_LDS);
  k_fused<<<256, 512, DEC_LDS, stream>>>(xprojF, xprojB, WpF, WpB,
                                         memory, c0h0, W_mem, W_attn,
                                         decx, W_dec, W_out,
                                         sig_len, base_len,
                                         nhbuf, parts, flags, bigws ? 1 : 0,
                                         out);
}